// Round 6
// baseline (183.403 us; speedup 1.0000x reference)
//
#include <hip/hip_runtime.h>

// dense_image_warp R13: reg-staged RGBX float4 window, padded LDS stride,
// aligned ds_read_b128 gathers.
//
// R12 post-mortem: continuous-issue pipelining = null (63.7 us, hbm_gbps
// unchanged) -> duty theory dead. Across R7-R12 the invariant cost is the
// LDS gather: ~6 unaligned 12B-stride AoS reads/px (~27K cy/CU) + 5.6M
// conflict cycles (~22K cy/CU) from structural geometry (row stride 768B
// == 0 mod 128B: all window rows same bank phase; jittered-row lanes
// collide; barrier-coupled waves can't hide each other's stalls).
// global_load_lds forbids padding (m104) -> R13 reg-stages instead:
// dwordx3 load -> ds_write_b128 as RGBX float4. Buys: +1 float4 row pad
// (stride 1040B == 1 quad mod 8, rows decorrelated) and 16B-aligned px
// (one ds_read_b128 per corner, 4 LDS ops/px). Staging moves to the idle
// VALU/VMEM pipes. Window 65x65(pad) f4 = 67.6 KB -> 2 blocks/CU.

constexpr int B = 8;
constexpr int H = 1024;
constexpr int W = 768;
constexpr int C = 3;

constexpr int TY = 32, TX = 32;          // output tile
constexpr int WIN_ROWS = 65;             // TY + 16 up + 16 down + 1
constexpr int WIN_COLS = 64;             // TX + 16 halo each side
constexpr int LSTRIDE = WIN_COLS + 1;    // 65 float4 = 1040 B: +1 quad/row
constexpr int WIN_PX = WIN_ROWS * WIN_COLS;      // 4160 staged pixels
constexpr int TILES_X = W / TX;          // 24
constexpr int TILES_Y = H / TY;          // 32
constexpr int TILES_PER_B = TILES_X * TILES_Y;   // 768

constexpr int NTHREADS = 512;            // 8 waves/block
constexpr int SITER = (WIN_PX + NTHREADS - 1) / NTHREADS;   // 9 (last partial)
constexpr int PX_PER_T = (TY * TX) / NTHREADS;   // 2

typedef float vfloat2 __attribute__((ext_vector_type(2)));
typedef float vfloat4 __attribute__((ext_vector_type(4)));
typedef float vfloat2_a4 __attribute__((ext_vector_type(2), aligned(4)));
typedef float vfloat4_a4 __attribute__((ext_vector_type(4), aligned(4)));

__global__ __launch_bounds__(NTHREADS, 4) void warp_kernel(
    const float* __restrict__ image,   // [B,H,W,3]
    const float* __restrict__ flow,    // [B,H,W,2]
    float* __restrict__ out)           // [B,H,W,3]
{
    __shared__ vfloat4 win4[WIN_ROWS * LSTRIDE];   // 4225 * 16 = 67600 B

    // ---- XCD-aware decomposition: blockIdx%8 = XCD = batch ----
    const int flat = blockIdx.x;            // 0..6143
    const int b    = flat & 7;
    const int s    = flat >> 3;             // temporal order within XCD
    const int ty   = s / TILES_X;
    const int tx   = s - ty * TILES_X;
    const int Y0 = ty * TY, X0 = tx * TX;

    const int rowLo = min(max(Y0 - 16, 0), H - WIN_ROWS);
    const int colLo = min(max(X0 - 16, 0), W - WIN_COLS);

    // ---- stage phase A: issue all global loads (coalesced 12B/lane) ----
    const float* gwin = image + ((size_t)b * H + rowLo) * (W * C) + colLo * C;
    float sr[SITER], sg[SITER], sb[SITER];
#pragma unroll
    for (int i = 0; i < SITER; ++i) {
        const int p = threadIdx.x + i * NTHREADS;
        if (i < SITER - 1 || p < WIN_PX) {        // only iter 8 is partial
            const int r = p >> 6;                 // window cols == 64
            const int c = p & 63;
            const float* g = gwin + r * (W * C) + c * 3;
            sr[i] = g[0]; sg[i] = g[1]; sb[i] = g[2];
        }
    }

    // ---- flow loads: latency hides under staging loads ----
    vfloat2 f[PX_PER_T];
#pragma unroll
    for (int k = 0; k < PX_PER_T; ++k) {
        const int p   = threadIdx.x + k * NTHREADS;
        const int py  = p >> 5;
        const int pxx = p & 31;
        const size_t pix = ((size_t)b * H + (Y0 + py)) * W + (X0 + pxx);
        f[k] = __builtin_nontemporal_load((const vfloat2*)flow + pix);
    }

    // ---- stage phase B: RGBX writes into padded layout ----
#pragma unroll
    for (int i = 0; i < SITER; ++i) {
        const int p = threadIdx.x + i * NTHREADS;
        if (i < SITER - 1 || p < WIN_PX) {
            const int r = p >> 6;
            const int c = p & 63;
            win4[r * LSTRIDE + c] = (vfloat4){sr[i], sg[i], sb[i], 0.0f};
        }
    }

    __syncthreads();

    // ---- compute: 2 px per thread, one b128 per corner ----
#pragma unroll
    for (int k = 0; k < PX_PER_T; ++k) {
        const int p   = threadIdx.x + k * NTHREADS;
        const int py  = p >> 5;
        const int pxx = p & 31;
        const int y = Y0 + py;
        const int x = X0 + pxx;
        const size_t pix = ((size_t)b * H + y) * W + x;

        const float qy = (float)y - f[k].x;
        const float qx = (float)x - f[k].y;

        float y0f = floorf(qy);
        float x0f = floorf(qx);
        y0f = fminf(fmaxf(y0f, 0.0f), (float)(H - 2));
        x0f = fminf(fmaxf(x0f, 0.0f), (float)(W - 2));
        const float ay = fminf(fmaxf(qy - y0f, 0.0f), 1.0f);
        const float ax = fminf(fmaxf(qx - x0f, 0.0f), 1.0f);

        const int y0 = (int)y0f;
        const int x0 = (int)x0f;

        float tl0, tl1, tl2, tr0, tr1, tr2, bl0, bl1, bl2, br0, br1, br2;

        const bool inwin = (y0 >= rowLo) & (y0 <= rowLo + WIN_ROWS - 2) &
                           (x0 >= colLo) & (x0 <= colLo + WIN_COLS - 2);
        if (inwin) {
            const int idx = (y0 - rowLo) * LSTRIDE + (x0 - colLo);
            const vfloat4 tl = win4[idx];
            const vfloat4 tr = win4[idx + 1];
            const vfloat4 bl = win4[idx + LSTRIDE];
            const vfloat4 br = win4[idx + LSTRIDE + 1];
            tl0 = tl.x; tl1 = tl.y; tl2 = tl.z;
            tr0 = tr.x; tr1 = tr.y; tr2 = tr.z;
            bl0 = bl.x; bl1 = bl.y; bl2 = bl.z;
            br0 = br.x; br1 = br.y; br2 = br.z;
        } else {
            // rare (~0.4% px): flow beyond halo -> direct global bilinear
            const float* top = image + (((size_t)b * H + y0) * W + x0) * C;
            const float* bot = top + (size_t)W * C;
            const vfloat4 t4 = *(const vfloat4_a4*)top;
            const vfloat2 t2 = *(const vfloat2_a4*)(top + 4);
            const vfloat4 b4 = *(const vfloat4_a4*)bot;
            const vfloat2 b2 = *(const vfloat2_a4*)(bot + 4);
            tl0 = t4.x; tl1 = t4.y; tl2 = t4.z;
            tr0 = t4.w; tr1 = t2.x; tr2 = t2.y;
            bl0 = b4.x; bl1 = b4.y; bl2 = b4.z;
            br0 = b4.w; br1 = b2.x; br2 = b2.y;
        }

        const float tp0 = tl0 + ax * (tr0 - tl0);
        const float tp1 = tl1 + ax * (tr1 - tl1);
        const float tp2 = tl2 + ax * (tr2 - tl2);
        const float bo0 = bl0 + ax * (br0 - bl0);
        const float bo1 = bl1 + ax * (br1 - bl1);
        const float bo2 = bl2 + ax * (br2 - bl2);

        float* o = out + pix * C;
        __builtin_nontemporal_store(tp0 + ay * (bo0 - tp0), &o[0]);
        __builtin_nontemporal_store(tp1 + ay * (bo1 - tp1), &o[1]);
        __builtin_nontemporal_store(tp2 + ay * (bo2 - tp2), &o[2]);
    }
}

extern "C" void kernel_launch(void* const* d_in, const int* in_sizes, int n_in,
                              void* d_out, int out_size, void* d_ws, size_t ws_size,
                              hipStream_t stream) {
    const float* image = (const float*)d_in[0];
    const float* flow  = (const float*)d_in[1];
    float* out = (float*)d_out;

    dim3 grid(B * TILES_PER_B);   // 6144 blocks, 12 rounds of 2/CU
    dim3 block(NTHREADS);
    warp_kernel<<<grid, block, 0, stream>>>(image, flow, out);
}

// Round 7
// 179.081 us; speedup vs baseline: 1.0241x; 1.0241x over previous
//
#include <hip/hip_runtime.h>

// dense_image_warp R14: RGBX texels staged directly by global_load_lds
// (per-lane 12B-stride sources, 16B loads), padded 63-texel row stride,
// one aligned ds_read_b128 per bilinear corner.
//
// R13 post-mortem: conflicts -43% but time +7% -- reg-staging round-trip
// cost more than the conflict cut gained; conflict lever ~dead at the 3M
// level. R14 gets R13's layout at R7's staging cost using the m104 rule:
// global_load_lds's LDS dest is lane-linear but the GLOBAL SRC is per-lane
// arbitrary. Issue 16B loads at 12B-stride pixel addresses -> LDS holds
// RGBX texels (w = next px's R, never read) with no VGPR traffic and no
// ds_write. Window 65x63 texels: row stride 1008B != 0 mod 128 -> rows on
// different bank quads (kills R7's structural collision geometry); each
// corner = one aligned ds_read_b128 (4 LDS ops/px vs ~6 unaligned).
// 64KB LDS -> 2 blocks/CU. colLo <= 704 keeps all 16B reads in-bounds.

constexpr int B = 8;
constexpr int H = 1024;
constexpr int W = 768;
constexpr int C = 3;

constexpr int TY = 32, TX = 32;          // output tile
constexpr int WIN_ROWS = 65;             // TY + 16 up + 16 down + 1
constexpr int WIN_COLS = 63;             // TX + 15 left + 16 right halo
constexpr int WIN_PX = WIN_ROWS * WIN_COLS;      // 4095 texels
constexpr int TILES_X = W / TX;          // 24
constexpr int TILES_Y = H / TY;          // 32
constexpr int TILES_PER_B = TILES_X * TILES_Y;   // 768

constexpr int NTHREADS = 512;            // 8 waves/block
constexpr int NWAVES = NTHREADS / 64;
constexpr int ISSUES = (WIN_PX + 63) / 64;       // 64 wave-issues per block
constexpr int PX_PER_T = (TY * TX) / NTHREADS;   // 2

typedef float vfloat2 __attribute__((ext_vector_type(2)));
typedef float vfloat4 __attribute__((ext_vector_type(4)));
typedef float vfloat2_a4 __attribute__((ext_vector_type(2), aligned(4)));
typedef float vfloat4_a4 __attribute__((ext_vector_type(4), aligned(4)));

__global__ __launch_bounds__(NTHREADS, 4) void warp_kernel(
    const float* __restrict__ image,   // [B,H,W,3]
    const float* __restrict__ flow,    // [B,H,W,2]
    float* __restrict__ out)           // [B,H,W,3]
{
    // 4096 RGBX texels = 65536 B -> 2 blocks/CU. Texel 4095 is tail padding.
    __shared__ vfloat4 win4[4096];

    // ---- XCD-aware decomposition: blockIdx%8 = XCD = batch ----
    const int flat = blockIdx.x;            // 0..6143
    const int b    = flat & 7;
    const int s    = flat >> 3;             // temporal order within XCD
    const int ty   = s / TILES_X;
    const int tx   = s - ty * TILES_X;
    const int Y0 = ty * TY, X0 = tx * TX;

    const int rowLo = min(max(Y0 - 16, 0), H - WIN_ROWS);          // <= 959
    const int colLo = min(max(X0 - 15, 0), W - WIN_COLS - 1);      // <= 704

    const int lane = threadIdx.x & 63;
    const int wv   = threadIdx.x >> 6;      // 0..7

    // ---- async staging: 16B loads from 12B-stride pixel addresses ----
    // LDS dest = texel-linear (j*1024B + lane*16B). Texel (r,c) <- pixel
    // (rowLo+r, colLo+c) RGB + 4B of the next pixel (never read).
    const float* gwin = image + ((size_t)b * H + rowLo) * (W * C) + colLo * C;
#pragma unroll 1
    for (int i = 0; i < ISSUES / NWAVES; ++i) {
        const int j = i * NWAVES + wv;            // 0..63 wave-uniform
        int ci = j * 64 + lane;                   // texel index
        if (ci > WIN_PX - 1) ci = WIN_PX - 1;     // tail: dup px 4094
        const int r = ci / WIN_COLS;              // magic-mul div (63)
        const int c = ci - r * WIN_COLS;
        const float* g = gwin + (size_t)r * (W * C) + c * 3;
        __builtin_amdgcn_global_load_lds(
            (const __attribute__((address_space(1))) void*)g,
            (__attribute__((address_space(3))) void*)(win4 + (size_t)j * 64),
            16, 0, 0);
    }

    // ---- flow loads before barrier: latency hides under staging ----
    vfloat2 f[PX_PER_T];
#pragma unroll
    for (int k = 0; k < PX_PER_T; ++k) {
        const int p   = threadIdx.x + k * NTHREADS;
        const int py  = p >> 5;
        const int pxx = p & 31;
        const size_t pix = ((size_t)b * H + (Y0 + py)) * W + (X0 + pxx);
        f[k] = __builtin_nontemporal_load((const vfloat2*)flow + pix);
    }

    __syncthreads();   // drains vmcnt: staging + flow complete

    // ---- compute: 2 px per thread, one aligned b128 per corner ----
#pragma unroll
    for (int k = 0; k < PX_PER_T; ++k) {
        const int p   = threadIdx.x + k * NTHREADS;
        const int py  = p >> 5;
        const int pxx = p & 31;
        const int y = Y0 + py;
        const int x = X0 + pxx;
        const size_t pix = ((size_t)b * H + y) * W + x;

        const float qy = (float)y - f[k].x;
        const float qx = (float)x - f[k].y;

        float y0f = floorf(qy);
        float x0f = floorf(qx);
        y0f = fminf(fmaxf(y0f, 0.0f), (float)(H - 2));
        x0f = fminf(fmaxf(x0f, 0.0f), (float)(W - 2));
        const float ay = fminf(fmaxf(qy - y0f, 0.0f), 1.0f);
        const float ax = fminf(fmaxf(qx - x0f, 0.0f), 1.0f);

        const int y0 = (int)y0f;
        const int x0 = (int)x0f;

        float tl0, tl1, tl2, tr0, tr1, tr2, bl0, bl1, bl2, br0, br1, br2;

        const bool inwin = (y0 >= rowLo) & (y0 <= rowLo + WIN_ROWS - 2) &
                           (x0 >= colLo) & (x0 <= colLo + WIN_COLS - 2);
        if (inwin) {
            const int idx = (y0 - rowLo) * WIN_COLS + (x0 - colLo);
            const vfloat4 tl = win4[idx];
            const vfloat4 tr = win4[idx + 1];
            const vfloat4 bl = win4[idx + WIN_COLS];
            const vfloat4 br = win4[idx + WIN_COLS + 1];
            tl0 = tl.x; tl1 = tl.y; tl2 = tl.z;
            tr0 = tr.x; tr1 = tr.y; tr2 = tr.z;
            bl0 = bl.x; bl1 = bl.y; bl2 = bl.z;
            br0 = br.x; br1 = br.y; br2 = br.z;
        } else {
            // rare (~0.4% px): flow beyond halo -> direct global bilinear
            const float* top = image + (((size_t)b * H + y0) * W + x0) * C;
            const float* bot = top + (size_t)W * C;
            const vfloat4 t4 = *(const vfloat4_a4*)top;
            const vfloat2 t2 = *(const vfloat2_a4*)(top + 4);
            const vfloat4 b4 = *(const vfloat4_a4*)bot;
            const vfloat2 b2 = *(const vfloat2_a4*)(bot + 4);
            tl0 = t4.x; tl1 = t4.y; tl2 = t4.z;
            tr0 = t4.w; tr1 = t2.x; tr2 = t2.y;
            bl0 = b4.x; bl1 = b4.y; bl2 = b4.z;
            br0 = b4.w; br1 = b2.x; br2 = b2.y;
        }

        const float tp0 = tl0 + ax * (tr0 - tl0);
        const float tp1 = tl1 + ax * (tr1 - tl1);
        const float tp2 = tl2 + ax * (tr2 - tl2);
        const float bo0 = bl0 + ax * (br0 - bl0);
        const float bo1 = bl1 + ax * (br1 - bl1);
        const float bo2 = bl2 + ax * (br2 - bl2);

        float* o = out + pix * C;
        __builtin_nontemporal_store(tp0 + ay * (bo0 - tp0), &o[0]);
        __builtin_nontemporal_store(tp1 + ay * (bo1 - tp1), &o[1]);
        __builtin_nontemporal_store(tp2 + ay * (bo2 - tp2), &o[2]);
    }
}

extern "C" void kernel_launch(void* const* d_in, const int* in_sizes, int n_in,
                              void* d_out, int out_size, void* d_ws, size_t ws_size,
                              hipStream_t stream) {
    const float* image = (const float*)d_in[0];
    const float* flow  = (const float*)d_in[1];
    float* out = (float*)d_out;

    dim3 grid(B * TILES_PER_B);   // 6144 blocks, 12 rounds of 2/CU
    dim3 block(NTHREADS);
    warp_kernel<<<grid, block, 0, stream>>>(image, flow, out);
}